// Round 1
// baseline (34.168 us; speedup 1.0000x reference)
//
#include <hip/hip_runtime.h>
#include <hip/hip_bf16.h>

// out[i] = exp(-0.5 * 0.54 * ((x[i,0]-mu0)^2 + (x[i,1]-mu1)^2))
// Memory-bound: 12 B/row traffic. Vectorize: one float4 load = 2 rows,
// one float2 store = 2 outputs per lane per iteration.

__global__ void gauss_pdf_kernel(const float4* __restrict__ x,
                                 const float* __restrict__ mu,
                                 float2* __restrict__ out,
                                 int n_pairs) {
    const float m0 = mu[0];
    const float m1 = mu[1];
    const float k = -0.5f * 0.54f;  // -0.27

    int idx = blockIdx.x * blockDim.x + threadIdx.x;
    int stride = gridDim.x * blockDim.x;
    for (int i = idx; i < n_pairs; i += stride) {
        float4 v = x[i];  // rows 2i and 2i+1: (x0,y0,x1,y1)
        float d0 = v.x - m0;
        float d1 = v.y - m1;
        float d2 = v.z - m0;
        float d3 = v.w - m1;
        float q0 = (d0 * d0 + d1 * d1) * k;
        float q1 = (d2 * d2 + d3 * d3) * k;
        float2 r;
        r.x = __expf(q0);
        r.y = __expf(q1);
        out[i] = r;
    }
}

extern "C" void kernel_launch(void* const* d_in, const int* in_sizes, int n_in,
                              void* d_out, int out_size, void* d_ws, size_t ws_size,
                              hipStream_t stream) {
    const float* x = (const float*)d_in[0];   // [N,2] f32
    const float* mu = (const float*)d_in[1];  // [2] f32
    float* out = (float*)d_out;               // [N] f32

    int N = in_sizes[0] / 2;       // 16777216
    int n_pairs = N / 2;           // 8388608 (N is even)

    const int block = 256;
    int grid = (n_pairs + block - 1) / block;
    const int max_grid = 2048;     // 256 CUs * 8 blocks, grid-stride the rest
    if (grid > max_grid) grid = max_grid;

    gauss_pdf_kernel<<<grid, block, 0, stream>>>(
        (const float4*)x, mu, (float2*)out, n_pairs);
}